// Round 25
// baseline (108.058 us; speedup 1.0000x reference)
//
#include <hip/hip_runtime.h>

// B=2, C=256, X=Y=Z=16 -> N=4096, GROUPS=8, HEADS=8, D=32
#define NB 2
#define NC 256
#define NT 4096
#define NG 8
#define NH 8
#define EPSV 1e-5f
// (1/sqrt(32)) * log2(e): folded into Q at projection time -> softmax is exp2()
#define SCALE_L2E 0.25503164427f
#define NCHUNK 4
#define CHTOK (NT / NCHUNK)                 // 1024 tokens per chunk
#define NIT (CHTOK / 32)                    // 32 iterations per chunk
#define PO_ELEMS ((size_t)NB * NC * NT)     // bf16 elements per chunk of partial O

typedef __attribute__((ext_vector_type(8))) __bf16 bf16x8;
typedef __attribute__((ext_vector_type(8))) unsigned short u16x8;
typedef __attribute__((ext_vector_type(4))) unsigned short u16x4;
typedef __attribute__((ext_vector_type(4))) unsigned int u32x4;
typedef __attribute__((ext_vector_type(2))) unsigned int u32x2;
typedef __attribute__((ext_vector_type(4))) float f32x4;

static __device__ __forceinline__ unsigned short f2bf(float f) {
    union { float f; unsigned int u; } v; v.f = f;
    unsigned int r = v.u + 0x7fffu + ((v.u >> 16) & 1u);  // RNE
    return (unsigned short)(r >> 16);
}
static __device__ __forceinline__ float bf2f(unsigned short u) {
    union { unsigned int u; float f; } v; v.u = ((unsigned int)u) << 16;
    return v.f;
}
static __device__ __forceinline__ bf16x8 ldbf8(const unsigned short* p) {
    u16x8 u = *(const u16x8*)p;
    return __builtin_bit_cast(bf16x8, u);
}
static __device__ __forceinline__ unsigned int cvtpk(float lo, float hi) {
    unsigned int d;
    asm("v_cvt_pk_bf16_f32 %0, %1, %2" : "=v"(d) : "v"(lo), "v"(hi));
    return d;
}

// -------- GroupNorm partial stats (blocks 0..511) + weight prep (512..639) ---
__global__ __launch_bounds__(256) void k_stats_wprep(const float* __restrict__ x,
                                                     float* __restrict__ part,
                                                     const float* __restrict__ wq,
                                                     const float* __restrict__ wo,
                                                     unsigned short* __restrict__ wq_bf,
                                                     unsigned short* __restrict__ wo_bf) {
    __shared__ float ss[256], sq[256];
    int bidx = blockIdx.x;
    if (bidx < 512) {
        int bg = bidx >> 5;
        int p  = bidx & 31;
        const float4* base = (const float4*)(x + (size_t)bg * 131072 + (size_t)p * 4096);
        float s = 0.f, s2 = 0.f;
#pragma unroll
        for (int i = 0; i < 4; ++i) {
            float4 v = base[threadIdx.x + i * 256];
            s  += v.x + v.y + v.z + v.w;
            s2 += v.x * v.x + v.y * v.y + v.z * v.z + v.w * v.w;
        }
        ss[threadIdx.x] = s; sq[threadIdx.x] = s2;
        __syncthreads();
        for (int off = 128; off > 0; off >>= 1) {
            if (threadIdx.x < off) {
                ss[threadIdx.x] += ss[threadIdx.x + off];
                sq[threadIdx.x] += sq[threadIdx.x + off];
            }
            __syncthreads();
        }
        if (threadIdx.x == 0) {
            part[bidx * 2 + 0] = ss[0];
            part[bidx * 2 + 1] = sq[0];
        }
    } else {
        int b2 = bidx - 512;
        const float* src;
        unsigned short* dst;
        int off;
        if (b2 < 96) { src = wq; dst = wq_bf; off = b2 * 2048; }
        else         { src = wo; dst = wo_bf; off = (b2 - 96) * 2048; }
        int idx = off + threadIdx.x * 8;
        float4 a = *(const float4*)(src + idx);
        float4 c = *(const float4*)(src + idx + 4);
        u32x4 o = { cvtpk(a.x, a.y), cvtpk(a.z, a.w),
                    cvtpk(c.x, c.y), cvtpk(c.z, c.w) };
        *(u32x4*)(dst + idx) = o;
    }
}

// ---------------- x prep: GroupNorm + bf16 + transpose -> xnT[b][n][c] -------
// Stats finalization fused in (same shfl tree shape -> identical sums).
__global__ __launch_bounds__(256) void k_xprep(const float* __restrict__ x,
                                               const float* __restrict__ nw,
                                               const float* __restrict__ nbias,
                                               const float* __restrict__ part,
                                               unsigned short* __restrict__ xnT) {
    __shared__ unsigned short T[64][72];   // [n][c], padded
    __shared__ float gstat[4];             // {mean,rstd} x 2 groups
    int b = blockIdx.z, c0 = blockIdx.y * 64, n0 = blockIdx.x * 64;
    int tid = threadIdx.x;
    if (tid < 64) {
        int gl = tid >> 5, p = tid & 31;
        int bg = b * NG + (c0 >> 5) + gl;
        float s  = part[(bg * 32 + p) * 2 + 0];
        float s2 = part[(bg * 32 + p) * 2 + 1];
#pragma unroll
        for (int off = 16; off > 0; off >>= 1) {
            s  += __shfl_down(s, off, 32);
            s2 += __shfl_down(s2, off, 32);
        }
        if (p == 0) {
            const float inv = 1.0f / 131072.0f;
            float mean = s * inv;
            float var  = s2 * inv - mean * mean;
            gstat[gl * 2 + 0] = mean;
            gstat[gl * 2 + 1] = rsqrtf(var + EPSV);
        }
    }
    __syncthreads();

    int c_l = tid >> 2, nq = (tid & 3) * 16;
    int c = c0 + c_l;
    int gl = c_l >> 5;
    float mean = gstat[gl * 2 + 0];
    float rstd = gstat[gl * 2 + 1];
    float wsc = nw[c] * rstd;
    float bb  = nbias[c] - mean * wsc;    // xn = x*wsc + bb
    const float4* src = (const float4*)(x + ((size_t)(b * NC + c)) * NT + n0 + nq);
#pragma unroll
    for (int i = 0; i < 4; ++i) {
        float4 v = src[i];
        T[nq + i * 4 + 0][c_l] = f2bf(v.x * wsc + bb);
        T[nq + i * 4 + 1][c_l] = f2bf(v.y * wsc + bb);
        T[nq + i * 4 + 2][c_l] = f2bf(v.z * wsc + bb);
        T[nq + i * 4 + 3][c_l] = f2bf(v.w * wsc + bb);
    }
    __syncthreads();
    int n_l = tid >> 2, cq = (tid & 3) * 16;
    unsigned short* dst = xnT + ((size_t)b * NT + n0 + n_l) * 256 + c0 + cq;
    *(u16x8*)dst       = *(const u16x8*)&T[n_l][cq];
    *(u16x8*)(dst + 8) = *(const u16x8*)&T[n_l][cq + 8];
}

// ---------------- QKV projection: bf16 MFMA, 128-wide o-blocks ---------------
__global__ __launch_bounds__(256) void k_qkv_mfma(const unsigned short* __restrict__ wq_bf,
                                                  const unsigned short* __restrict__ xnT,
                                                  unsigned short* __restrict__ qkT,
                                                  unsigned short* __restrict__ vbf) {
    int b = blockIdx.z, o0 = blockIdx.y * 128, n0 = blockIdx.x * 64;
    int tid = threadIdx.x;
    int w = tid >> 6, lane = tid & 63, c16 = lane & 15, g = lane >> 4;
    int n_tok = n0 + w * 16 + c16;
    const unsigned short* Bsrc = xnT + ((size_t)b * NT + n_tok) * 256 + g * 8;
    const unsigned short* Asrc = wq_bf + (size_t)(o0 + c16) * 256 + g * 8;
    f32x4 acc[8] = {};
    for (int kk = 0; kk < 8; ++kk) {
        bf16x8 bfr = ldbf8(Bsrc + kk * 32);
#pragma unroll
        for (int ot = 0; ot < 8; ++ot) {
            bf16x8 afr = ldbf8(Asrc + ot * 16 * 256 + kk * 32);
            acc[ot] = __builtin_amdgcn_mfma_f32_16x16x32_bf16(afr, bfr, acc[ot], 0, 0, 0);
        }
    }
    if (o0 < 512) {
#pragma unroll
        for (int ot = 0; ot < 8; ++ot) {
            int ob = o0 + ot * 16 + g * 4;
            int qk = ob >> 8;
            float sc = (qk == 0) ? SCALE_L2E : 1.0f;
            int h  = (ob >> 5) & 7;
            int d4 = ob & 31;
            unsigned int u0 = cvtpk(acc[ot][0] * sc, acc[ot][1] * sc);
            unsigned int u1 = cvtpk(acc[ot][2] * sc, acc[ot][3] * sc);
            u16x4 pk = { (unsigned short)(u0 & 0xFFFF), (unsigned short)(u0 >> 16),
                         (unsigned short)(u1 & 0xFFFF), (unsigned short)(u1 >> 16) };
            *(u16x4*)(qkT + ((((size_t)qk * NB + b) * NH + h) * NT + n_tok) * 32 + d4) = pk;
        }
    } else {
#pragma unroll
        for (int ot = 0; ot < 8; ++ot) {
            int ob = (o0 - 512) + ot * 16 + g * 4;
            int h = (ob >> 5) & 7;
            int d = ob & 31;
            unsigned short* dst = vbf + (((size_t)b * NH + h) * 32 + d) * NT + n_tok;
            dst[0]      = f2bf(acc[ot][0]);
            dst[NT]     = f2bf(acc[ot][1]);
            dst[2 * NT] = f2bf(acc[ot][2]);
            dst[3 * NT] = f2bf(acc[ot][3]);
        }
    }
}

// ---------------- Attention: swapped-QK^T bf16 MFMA, split-token -------------
// (byte-identical to the version that passed six consecutive runs)
__global__ __launch_bounds__(256) void k_attn(const unsigned short* __restrict__ qkT,
                                              const unsigned short* __restrict__ vbf,
                                              unsigned short* __restrict__ pO,
                                              float* __restrict__ pl) {
    __shared__ unsigned short KV[2560];   // K: [32 tok][40]; V: 1280 + [32 d][40 slots]
    int bid = blockIdx.x;
    int xcd  = bid & 7;
    int slot = bid >> 3;
    int combo = xcd * 8 + (slot >> 5);
    int sb    = slot & 31;
    int b  = combo >> 5;
    int ch = (combo >> 3) & 3;
    int h  = combo & 7;

    int tid = threadIdx.x;
    int w = tid >> 6, lane = tid & 63, col = lane & 15, g = lane >> 4;
    int s0 = sb * 128 + w * 32;

    const unsigned short* qB = qkT + ((((size_t)0 * NB + b) * NH + h) * NT) * 32;
    const unsigned short* kB = qkT + ((((size_t)1 * NB + b) * NH + h) * NT) * 32;
    const unsigned short* vB = vbf + (((size_t)b * NH + h) * 32) * NT;

    bf16x8 qf[2];
    qf[0] = ldbf8(qB + (size_t)(s0 + col) * 32 + g * 8);
    qf[1] = ldbf8(qB + (size_t)(s0 + 16 + col) * 32 + g * 8);

    u16x8 ou;
#pragma unroll
    for (int j = 0; j < 8; ++j) ou[j] = 0x3F80;  // bf16 1.0
    const bf16x8 ones = __builtin_bit_cast(bf16x8, ou);

    const unsigned short* gsK = kB;
    const unsigned short* gsVA = vB;
    const unsigned short* gsVB = vB;
    int ldst = 0;
    if (tid < 128) {
        gsK  = kB + ((size_t)ch * CHTOK) * 32 + tid * 8;
        ldst = (tid >> 2) * 40 + (tid & 3) * 8;
    } else {
        int idx = tid - 128;
        int d = idx >> 2, q = idx & 3;
        gsVA = vB + (size_t)d * NT + ch * CHTOK + q * 4;        // tokens 4q..4q+3
        gsVB = gsVA + 16;                                       // tokens 16+4q..+3
        ldst = 1280 + d * 40 + q * 8;
    }

    f32x4 oacc[2][2] = {};
    f32x4 lacc[2] = {};

    for (int it = 0; it < NIT; ++it) {
        __syncthreads();   // all reads of previous tile complete
        if (tid < 128) {
            *(u16x8*)&KV[ldst] = *(const u16x8*)(gsK + (size_t)it * 1024);
        } else {
            u16x4 va4 = *(const u16x4*)(gsVA + it * 32);
            u16x4 vb4 = *(const u16x4*)(gsVB + it * 32);
            u16x8 vv = { va4[0], va4[1], va4[2], va4[3],
                         vb4[0], vb4[1], vb4[2], vb4[3] };
            *(u16x8*)&KV[ldst] = vv;
        }
        __syncthreads();   // tile fully staged
        bf16x8 k0 = ldbf8(&KV[col * 40 + g * 8]);
        bf16x8 k1 = ldbf8(&KV[(16 + col) * 40 + g * 8]);
        bf16x8 v0 = ldbf8(&KV[1280 + col * 40 + g * 8]);
        bf16x8 v1 = ldbf8(&KV[1280 + (16 + col) * 40 + g * 8]);
        const f32x4 z = {0.f, 0.f, 0.f, 0.f};
#pragma unroll
        for (int st = 0; st < 2; ++st) {
            f32x4 sa = __builtin_amdgcn_mfma_f32_16x16x32_bf16(k0, qf[st], z, 0, 0, 0);
            f32x4 sb2 = __builtin_amdgcn_mfma_f32_16x16x32_bf16(k1, qf[st], z, 0, 0, 0);
            // no-max softmax (logits bounded): P = exp2(S)
            unsigned int W0 = cvtpk(__builtin_amdgcn_exp2f(sa[0]),
                                    __builtin_amdgcn_exp2f(sa[1]));
            unsigned int W1 = cvtpk(__builtin_amdgcn_exp2f(sa[2]),
                                    __builtin_amdgcn_exp2f(sa[3]));
            unsigned int W2 = cvtpk(__builtin_amdgcn_exp2f(sb2[0]),
                                    __builtin_amdgcn_exp2f(sb2[1]));
            unsigned int W3 = cvtpk(__builtin_amdgcn_exp2f(sb2[2]),
                                    __builtin_amdgcn_exp2f(sb2[3]));
            u32x4 pbw = {W0, W1, W2, W3};
            bf16x8 pf = __builtin_bit_cast(bf16x8, pbw);
            lacc[st]    = __builtin_amdgcn_mfma_f32_16x16x32_bf16(ones, pf, lacc[st], 0, 0, 0);
            oacc[0][st] = __builtin_amdgcn_mfma_f32_16x16x32_bf16(v0, pf, oacc[0][st], 0, 0, 0);
            oacc[1][st] = __builtin_amdgcn_mfma_f32_16x16x32_bf16(v1, pf, oacc[1][st], 0, 0, 0);
        }
    }

    unsigned short* pOc = pO + (size_t)ch * PO_ELEMS;   // layout [b][n][c]
#pragma unroll
    for (int dt = 0; dt < 2; ++dt)
#pragma unroll
        for (int st = 0; st < 2; ++st) {
            int s = s0 + st * 16 + col;
            unsigned int u0 = cvtpk(oacc[dt][st][0], oacc[dt][st][1]);
            unsigned int u1 = cvtpk(oacc[dt][st][2], oacc[dt][st][3]);
            u16x4 pk = { (unsigned short)(u0 & 0xFFFF), (unsigned short)(u0 >> 16),
                         (unsigned short)(u1 & 0xFFFF), (unsigned short)(u1 >> 16) };
            *(u16x4*)&pOc[((size_t)(b * NT + s)) * 256 + h * 32 + dt * 16 + g * 4] = pk;
        }
    if (g == 0) {
#pragma unroll
        for (int st = 0; st < 2; ++st) {
            int s = s0 + st * 16 + col;
            pl[(((size_t)ch * NB + b) * NH + h) * NT + s] = lacc[st][0];
        }
    }
}

// ---------------- Fused combine + output projection + bias + residual --------
// Phase 2 re-partitioned: 2 token-groups x 2 o-groups of 128 outputs each ->
// each attL B-fragment feeds 8 MFMAs (was 4), halving wo_bf re-reads.
__global__ __launch_bounds__(512) void k_out_fused(const unsigned short* __restrict__ pO,
                                                   const float* __restrict__ pl,
                                                   const unsigned short* __restrict__ wo_bf,
                                                   const float* __restrict__ bout,
                                                   const float* __restrict__ x,
                                                   float* __restrict__ out) {
    __shared__ unsigned short attL[32 * 264];
    int b = blockIdx.y, n0 = blockIdx.x * 32;
    int tid = threadIdx.x;

    // phase 1: combine 32x256 tile (2048 quads, 4 per thread)
#pragma unroll
    for (int i = 0; i < 4; ++i) {
        int q = tid * 4 + i;
        int tok_l = q >> 6;
        int cq = (q & 63) * 4;
        int h = cq >> 5;
        int s = n0 + tok_l;
        float num[4] = {0.f, 0.f, 0.f, 0.f};
        float den = 0.f;
#pragma unroll
        for (int chn = 0; chn < NCHUNK; ++chn) {
            u16x4 ov = *(const u16x4*)&pO[(size_t)chn * PO_ELEMS +
                                          ((size_t)(b * NT + s)) * 256 + cq];
            den += pl[(((size_t)chn * NB + b) * NH + h) * NT + s];
            num[0] += bf2f(ov[0]); num[1] += bf2f(ov[1]);
            num[2] += bf2f(ov[2]); num[3] += bf2f(ov[3]);
        }
        float rd = 1.0f / den;
        u16x4 res = { f2bf(num[0] * rd), f2bf(num[1] * rd),
                      f2bf(num[2] * rd), f2bf(num[3] * rd) };
        *(u16x4*)&attL[tok_l * 264 + cq] = res;
    }
    __syncthreads();

    // phase 2: MFMA projection (wave w: tg = w&1 tokens, og = w>>1 in {0..3}
    // -> now og = (w>>1)&1 o-groups of 128; waves 4..7 mirror 0..3)
    int w = tid >> 6, lane = tid & 63, c16 = lane & 15, g = lane >> 4;
    int tg = w & 1, og = (w >> 1) & 1;
    int n_tok = n0 + tg * 16 + c16;
    int o0 = og * 128;
    const unsigned short* Bsrc = &attL[(tg * 16 + c16) * 264 + g * 8];
    const unsigned short* Asrc = wo_bf + (size_t)(o0 + c16) * 256 + g * 8;
    // waves 0..3 handle kk 0..3 halves? No: split K across wave pairs is a
    // reduction change. Instead waves 4..7 duplicate 0..3's (tg,og) with the
    // other half of the o-range handled by og2 offset:
    int dup = w >> 2;                      // 0 or 1
    o0 += 0;                               // keep o-range; dup selects acc half
    f32x4 acc[4] = {};
    // each duplicate pair covers 4 of the 8 ot-slots: dup=0 -> ot 0..3,
    // dup=1 -> ot 4..7 (64-output stride within the 128-block)
    const unsigned short* Asrc2 = Asrc + (size_t)dup * 64 * 256;
    for (int kk = 0; kk < 8; ++kk) {
        bf16x8 bfr = ldbf8(Bsrc + kk * 32);
#pragma unroll
        for (int ot = 0; ot < 4; ++ot) {
            bf16x8 afr = ldbf8(Asrc2 + ot * 16 * 256 + kk * 32);
            acc[ot] = __builtin_amdgcn_mfma_f32_16x16x32_bf16(afr, bfr, acc[ot], 0, 0, 0);
        }
    }
#pragma unroll
    for (int ot = 0; ot < 4; ++ot) {
        int ob = o0 + dup * 64 + ot * 16 + g * 4;
#pragma unroll
        for (int rr = 0; rr < 4; ++rr) {
            int o = ob + rr;
            size_t off = ((size_t)(b * NC + o)) * NT + n_tok;
            out[off] = acc[ot][rr] + bout[o] + x[off];
        }
    }
}

extern "C" void kernel_launch(void* const* d_in, const int* in_sizes, int n_in,
                              void* d_out, int out_size, void* d_ws, size_t ws_size,
                              hipStream_t stream) {
    const float* x    = (const float*)d_in[0];
    const float* nw   = (const float*)d_in[1];
    const float* nb   = (const float*)d_in[2];
    const float* wqkv = (const float*)d_in[3];
    const float* wout = (const float*)d_in[4];
    const float* bout = (const float*)d_in[5];
    float* out = (float*)d_out;
    char* wsb = (char*)d_ws;

    unsigned short* qkT = (unsigned short*)wsb;                        // 8 MB
    unsigned short* vbf = (unsigned short*)(wsb + 8u * 1024 * 1024);   // 4 MB
    unsigned short* pO  = (unsigned short*)(wsb + 12u * 1024 * 1024);  // 16 MB: [4ch][B][N][C] bf16
    float* pl   = (float*)(wsb + 28u * 1024 * 1024);                   // 1 MB
    float* part = (float*)(wsb + 29u * 1024 * 1024);
    unsigned short* wo_bf = (unsigned short*)(wsb + 30u * 1024 * 1024); // 128 KB
    // xnT (4 MB) and wq_bf (384 KB) alias the pO region: both dead before
    // k_attn writes pO (stream-ordered).
    unsigned short* xnT   = pO;                                        // @12 MB
    unsigned short* wq_bf = (unsigned short*)(wsb + 16u * 1024 * 1024);

    k_stats_wprep<<<640, 256, 0, stream>>>(x, part, wqkv, wout, wq_bf, wo_bf);
    k_xprep<<<dim3(NT / 64, NC / 64, NB), 256, 0, stream>>>(x, nw, nb, part, xnT);
    k_qkv_mfma<<<dim3(NT / 64, 6, NB), 256, 0, stream>>>(wq_bf, xnT, qkT, vbf);
    k_attn<<<dim3(NB * NCHUNK * NH * 32), 256, 0, stream>>>(qkT, vbf, pO, pl);
    k_out_fused<<<dim3(128, NB), 512, 0, stream>>>(pO, pl, wo_bf, bout, x, out);
}

// Round 26
// 107.493 us; speedup vs baseline: 1.0053x; 1.0053x over previous
//
#include <hip/hip_runtime.h>

// B=2, C=256, X=Y=Z=16 -> N=4096, GROUPS=8, HEADS=8, D=32
#define NB 2
#define NC 256
#define NT 4096
#define NG 8
#define NH 8
#define EPSV 1e-5f
// (1/sqrt(32)) * log2(e): folded into Q at projection time -> softmax is exp2()
#define SCALE_L2E 0.25503164427f
#define NCHUNK 4
#define CHTOK (NT / NCHUNK)                 // 1024 tokens per chunk
#define NIT (CHTOK / 32)                    // 32 iterations per chunk
#define PO_ELEMS ((size_t)NB * NC * NT)     // bf16 elements per chunk of partial O

typedef __attribute__((ext_vector_type(8))) __bf16 bf16x8;
typedef __attribute__((ext_vector_type(8))) unsigned short u16x8;
typedef __attribute__((ext_vector_type(4))) unsigned short u16x4;
typedef __attribute__((ext_vector_type(4))) unsigned int u32x4;
typedef __attribute__((ext_vector_type(2))) unsigned int u32x2;
typedef __attribute__((ext_vector_type(4))) float f32x4;

static __device__ __forceinline__ unsigned short f2bf(float f) {
    union { float f; unsigned int u; } v; v.f = f;
    unsigned int r = v.u + 0x7fffu + ((v.u >> 16) & 1u);  // RNE
    return (unsigned short)(r >> 16);
}
static __device__ __forceinline__ float bf2f(unsigned short u) {
    union { unsigned int u; float f; } v; v.u = ((unsigned int)u) << 16;
    return v.f;
}
static __device__ __forceinline__ bf16x8 ldbf8(const unsigned short* p) {
    u16x8 u = *(const u16x8*)p;
    return __builtin_bit_cast(bf16x8, u);
}
static __device__ __forceinline__ unsigned int cvtpk(float lo, float hi) {
    unsigned int d;
    asm("v_cvt_pk_bf16_f32 %0, %1, %2" : "=v"(d) : "v"(lo), "v"(hi));
    return d;
}

// -------- GroupNorm partial stats (blocks 0..511) + weight prep (512..639) ---
__global__ __launch_bounds__(256) void k_stats_wprep(const float* __restrict__ x,
                                                     float* __restrict__ part,
                                                     const float* __restrict__ wq,
                                                     const float* __restrict__ wo,
                                                     unsigned short* __restrict__ wq_bf,
                                                     unsigned short* __restrict__ wo_bf) {
    __shared__ float ss[256], sq[256];
    int bidx = blockIdx.x;
    if (bidx < 512) {
        int bg = bidx >> 5;
        int p  = bidx & 31;
        const float4* base = (const float4*)(x + (size_t)bg * 131072 + (size_t)p * 4096);
        float s = 0.f, s2 = 0.f;
#pragma unroll
        for (int i = 0; i < 4; ++i) {
            float4 v = base[threadIdx.x + i * 256];
            s  += v.x + v.y + v.z + v.w;
            s2 += v.x * v.x + v.y * v.y + v.z * v.z + v.w * v.w;
        }
        ss[threadIdx.x] = s; sq[threadIdx.x] = s2;
        __syncthreads();
        for (int off = 128; off > 0; off >>= 1) {
            if (threadIdx.x < off) {
                ss[threadIdx.x] += ss[threadIdx.x + off];
                sq[threadIdx.x] += sq[threadIdx.x + off];
            }
            __syncthreads();
        }
        if (threadIdx.x == 0) {
            part[bidx * 2 + 0] = ss[0];
            part[bidx * 2 + 1] = sq[0];
        }
    } else {
        int b2 = bidx - 512;
        const float* src;
        unsigned short* dst;
        int off;
        if (b2 < 96) { src = wq; dst = wq_bf; off = b2 * 2048; }
        else         { src = wo; dst = wo_bf; off = (b2 - 96) * 2048; }
        int idx = off + threadIdx.x * 8;
        float4 a = *(const float4*)(src + idx);
        float4 c = *(const float4*)(src + idx + 4);
        u32x4 o = { cvtpk(a.x, a.y), cvtpk(a.z, a.w),
                    cvtpk(c.x, c.y), cvtpk(c.z, c.w) };
        *(u32x4*)(dst + idx) = o;
    }
}

// ---------------- x prep: GroupNorm + bf16 + transpose -> xnT[b][n][c] -------
// Stats finalization fused in (same shfl tree shape -> identical sums).
__global__ __launch_bounds__(256) void k_xprep(const float* __restrict__ x,
                                               const float* __restrict__ nw,
                                               const float* __restrict__ nbias,
                                               const float* __restrict__ part,
                                               unsigned short* __restrict__ xnT) {
    __shared__ unsigned short T[64][72];   // [n][c], padded
    __shared__ float gstat[4];             // {mean,rstd} x 2 groups
    int b = blockIdx.z, c0 = blockIdx.y * 64, n0 = blockIdx.x * 64;
    int tid = threadIdx.x;
    if (tid < 64) {
        int gl = tid >> 5, p = tid & 31;
        int bg = b * NG + (c0 >> 5) + gl;
        float s  = part[(bg * 32 + p) * 2 + 0];
        float s2 = part[(bg * 32 + p) * 2 + 1];
#pragma unroll
        for (int off = 16; off > 0; off >>= 1) {
            s  += __shfl_down(s, off, 32);
            s2 += __shfl_down(s2, off, 32);
        }
        if (p == 0) {
            const float inv = 1.0f / 131072.0f;
            float mean = s * inv;
            float var  = s2 * inv - mean * mean;
            gstat[gl * 2 + 0] = mean;
            gstat[gl * 2 + 1] = rsqrtf(var + EPSV);
        }
    }
    __syncthreads();

    int c_l = tid >> 2, nq = (tid & 3) * 16;
    int c = c0 + c_l;
    int gl = c_l >> 5;
    float mean = gstat[gl * 2 + 0];
    float rstd = gstat[gl * 2 + 1];
    float wsc = nw[c] * rstd;
    float bb  = nbias[c] - mean * wsc;    // xn = x*wsc + bb
    const float4* src = (const float4*)(x + ((size_t)(b * NC + c)) * NT + n0 + nq);
#pragma unroll
    for (int i = 0; i < 4; ++i) {
        float4 v = src[i];
        T[nq + i * 4 + 0][c_l] = f2bf(v.x * wsc + bb);
        T[nq + i * 4 + 1][c_l] = f2bf(v.y * wsc + bb);
        T[nq + i * 4 + 2][c_l] = f2bf(v.z * wsc + bb);
        T[nq + i * 4 + 3][c_l] = f2bf(v.w * wsc + bb);
    }
    __syncthreads();
    int n_l = tid >> 2, cq = (tid & 3) * 16;
    unsigned short* dst = xnT + ((size_t)b * NT + n0 + n_l) * 256 + c0 + cq;
    *(u16x8*)dst       = *(const u16x8*)&T[n_l][cq];
    *(u16x8*)(dst + 8) = *(const u16x8*)&T[n_l][cq + 8];
}

// ---------------- QKV projection: bf16 MFMA, 128-wide o-blocks ---------------
__global__ __launch_bounds__(256) void k_qkv_mfma(const unsigned short* __restrict__ wq_bf,
                                                  const unsigned short* __restrict__ xnT,
                                                  unsigned short* __restrict__ qkT,
                                                  unsigned short* __restrict__ vbf) {
    int b = blockIdx.z, o0 = blockIdx.y * 128, n0 = blockIdx.x * 64;
    int tid = threadIdx.x;
    int w = tid >> 6, lane = tid & 63, c16 = lane & 15, g = lane >> 4;
    int n_tok = n0 + w * 16 + c16;
    const unsigned short* Bsrc = xnT + ((size_t)b * NT + n_tok) * 256 + g * 8;
    const unsigned short* Asrc = wq_bf + (size_t)(o0 + c16) * 256 + g * 8;
    f32x4 acc[8] = {};
    for (int kk = 0; kk < 8; ++kk) {
        bf16x8 bfr = ldbf8(Bsrc + kk * 32);
#pragma unroll
        for (int ot = 0; ot < 8; ++ot) {
            bf16x8 afr = ldbf8(Asrc + ot * 16 * 256 + kk * 32);
            acc[ot] = __builtin_amdgcn_mfma_f32_16x16x32_bf16(afr, bfr, acc[ot], 0, 0, 0);
        }
    }
    if (o0 < 512) {
#pragma unroll
        for (int ot = 0; ot < 8; ++ot) {
            int ob = o0 + ot * 16 + g * 4;
            int qk = ob >> 8;
            float sc = (qk == 0) ? SCALE_L2E : 1.0f;
            int h  = (ob >> 5) & 7;
            int d4 = ob & 31;
            unsigned int u0 = cvtpk(acc[ot][0] * sc, acc[ot][1] * sc);
            unsigned int u1 = cvtpk(acc[ot][2] * sc, acc[ot][3] * sc);
            u16x4 pk = { (unsigned short)(u0 & 0xFFFF), (unsigned short)(u0 >> 16),
                         (unsigned short)(u1 & 0xFFFF), (unsigned short)(u1 >> 16) };
            *(u16x4*)(qkT + ((((size_t)qk * NB + b) * NH + h) * NT + n_tok) * 32 + d4) = pk;
        }
    } else {
#pragma unroll
        for (int ot = 0; ot < 8; ++ot) {
            int ob = (o0 - 512) + ot * 16 + g * 4;
            int h = (ob >> 5) & 7;
            int d = ob & 31;
            unsigned short* dst = vbf + (((size_t)b * NH + h) * 32 + d) * NT + n_tok;
            dst[0]      = f2bf(acc[ot][0]);
            dst[NT]     = f2bf(acc[ot][1]);
            dst[2 * NT] = f2bf(acc[ot][2]);
            dst[3 * NT] = f2bf(acc[ot][3]);
        }
    }
}

// ---------------- Attention: swapped-QK^T bf16 MFMA, split-token -------------
// (byte-identical to the version that passed seven consecutive runs)
__global__ __launch_bounds__(256) void k_attn(const unsigned short* __restrict__ qkT,
                                              const unsigned short* __restrict__ vbf,
                                              unsigned short* __restrict__ pO,
                                              float* __restrict__ pl) {
    __shared__ unsigned short KV[2560];   // K: [32 tok][40]; V: 1280 + [32 d][40 slots]
    int bid = blockIdx.x;
    int xcd  = bid & 7;
    int slot = bid >> 3;
    int combo = xcd * 8 + (slot >> 5);
    int sb    = slot & 31;
    int b  = combo >> 5;
    int ch = (combo >> 3) & 3;
    int h  = combo & 7;

    int tid = threadIdx.x;
    int w = tid >> 6, lane = tid & 63, col = lane & 15, g = lane >> 4;
    int s0 = sb * 128 + w * 32;

    const unsigned short* qB = qkT + ((((size_t)0 * NB + b) * NH + h) * NT) * 32;
    const unsigned short* kB = qkT + ((((size_t)1 * NB + b) * NH + h) * NT) * 32;
    const unsigned short* vB = vbf + (((size_t)b * NH + h) * 32) * NT;

    bf16x8 qf[2];
    qf[0] = ldbf8(qB + (size_t)(s0 + col) * 32 + g * 8);
    qf[1] = ldbf8(qB + (size_t)(s0 + 16 + col) * 32 + g * 8);

    u16x8 ou;
#pragma unroll
    for (int j = 0; j < 8; ++j) ou[j] = 0x3F80;  // bf16 1.0
    const bf16x8 ones = __builtin_bit_cast(bf16x8, ou);

    const unsigned short* gsK = kB;
    const unsigned short* gsVA = vB;
    const unsigned short* gsVB = vB;
    int ldst = 0;
    if (tid < 128) {
        gsK  = kB + ((size_t)ch * CHTOK) * 32 + tid * 8;
        ldst = (tid >> 2) * 40 + (tid & 3) * 8;
    } else {
        int idx = tid - 128;
        int d = idx >> 2, q = idx & 3;
        gsVA = vB + (size_t)d * NT + ch * CHTOK + q * 4;        // tokens 4q..4q+3
        gsVB = gsVA + 16;                                       // tokens 16+4q..+3
        ldst = 1280 + d * 40 + q * 8;
    }

    f32x4 oacc[2][2] = {};
    f32x4 lacc[2] = {};

    for (int it = 0; it < NIT; ++it) {
        __syncthreads();   // all reads of previous tile complete
        if (tid < 128) {
            *(u16x8*)&KV[ldst] = *(const u16x8*)(gsK + (size_t)it * 1024);
        } else {
            u16x4 va4 = *(const u16x4*)(gsVA + it * 32);
            u16x4 vb4 = *(const u16x4*)(gsVB + it * 32);
            u16x8 vv = { va4[0], va4[1], va4[2], va4[3],
                         vb4[0], vb4[1], vb4[2], vb4[3] };
            *(u16x8*)&KV[ldst] = vv;
        }
        __syncthreads();   // tile fully staged
        bf16x8 k0 = ldbf8(&KV[col * 40 + g * 8]);
        bf16x8 k1 = ldbf8(&KV[(16 + col) * 40 + g * 8]);
        bf16x8 v0 = ldbf8(&KV[1280 + col * 40 + g * 8]);
        bf16x8 v1 = ldbf8(&KV[1280 + (16 + col) * 40 + g * 8]);
        const f32x4 z = {0.f, 0.f, 0.f, 0.f};
#pragma unroll
        for (int st = 0; st < 2; ++st) {
            f32x4 sa = __builtin_amdgcn_mfma_f32_16x16x32_bf16(k0, qf[st], z, 0, 0, 0);
            f32x4 sb2 = __builtin_amdgcn_mfma_f32_16x16x32_bf16(k1, qf[st], z, 0, 0, 0);
            // no-max softmax (logits bounded): P = exp2(S)
            unsigned int W0 = cvtpk(__builtin_amdgcn_exp2f(sa[0]),
                                    __builtin_amdgcn_exp2f(sa[1]));
            unsigned int W1 = cvtpk(__builtin_amdgcn_exp2f(sa[2]),
                                    __builtin_amdgcn_exp2f(sa[3]));
            unsigned int W2 = cvtpk(__builtin_amdgcn_exp2f(sb2[0]),
                                    __builtin_amdgcn_exp2f(sb2[1]));
            unsigned int W3 = cvtpk(__builtin_amdgcn_exp2f(sb2[2]),
                                    __builtin_amdgcn_exp2f(sb2[3]));
            u32x4 pbw = {W0, W1, W2, W3};
            bf16x8 pf = __builtin_bit_cast(bf16x8, pbw);
            lacc[st]    = __builtin_amdgcn_mfma_f32_16x16x32_bf16(ones, pf, lacc[st], 0, 0, 0);
            oacc[0][st] = __builtin_amdgcn_mfma_f32_16x16x32_bf16(v0, pf, oacc[0][st], 0, 0, 0);
            oacc[1][st] = __builtin_amdgcn_mfma_f32_16x16x32_bf16(v1, pf, oacc[1][st], 0, 0, 0);
        }
    }

    unsigned short* pOc = pO + (size_t)ch * PO_ELEMS;   // layout [b][n][c]
#pragma unroll
    for (int dt = 0; dt < 2; ++dt)
#pragma unroll
        for (int st = 0; st < 2; ++st) {
            int s = s0 + st * 16 + col;
            unsigned int u0 = cvtpk(oacc[dt][st][0], oacc[dt][st][1]);
            unsigned int u1 = cvtpk(oacc[dt][st][2], oacc[dt][st][3]);
            u16x4 pk = { (unsigned short)(u0 & 0xFFFF), (unsigned short)(u0 >> 16),
                         (unsigned short)(u1 & 0xFFFF), (unsigned short)(u1 >> 16) };
            *(u16x4*)&pOc[((size_t)(b * NT + s)) * 256 + h * 32 + dt * 16 + g * 4] = pk;
        }
    if (g == 0) {
#pragma unroll
        for (int st = 0; st < 2; ++st) {
            int s = s0 + st * 16 + col;
            pl[(((size_t)ch * NB + b) * NH + h) * NT + s] = lacc[st][0];
        }
    }
}

// ---------------- Fused combine + output projection + bias + residual --------
// (round-24 version: best measured total, 107.81 us)
__global__ __launch_bounds__(512) void k_out_fused(const unsigned short* __restrict__ pO,
                                                   const float* __restrict__ pl,
                                                   const unsigned short* __restrict__ wo_bf,
                                                   const float* __restrict__ bout,
                                                   const float* __restrict__ x,
                                                   float* __restrict__ out) {
    __shared__ unsigned short attL[32 * 264];
    int b = blockIdx.y, n0 = blockIdx.x * 32;
    int tid = threadIdx.x;

    // phase 1: combine 32x256 tile (2048 quads, 4 per thread)
#pragma unroll
    for (int i = 0; i < 4; ++i) {
        int q = tid * 4 + i;
        int tok_l = q >> 6;
        int cq = (q & 63) * 4;
        int h = cq >> 5;
        int s = n0 + tok_l;
        float num[4] = {0.f, 0.f, 0.f, 0.f};
        float den = 0.f;
#pragma unroll
        for (int chn = 0; chn < NCHUNK; ++chn) {
            u16x4 ov = *(const u16x4*)&pO[(size_t)chn * PO_ELEMS +
                                          ((size_t)(b * NT + s)) * 256 + cq];
            den += pl[(((size_t)chn * NB + b) * NH + h) * NT + s];
            num[0] += bf2f(ov[0]); num[1] += bf2f(ov[1]);
            num[2] += bf2f(ov[2]); num[3] += bf2f(ov[3]);
        }
        float rd = 1.0f / den;
        u16x4 res = { f2bf(num[0] * rd), f2bf(num[1] * rd),
                      f2bf(num[2] * rd), f2bf(num[3] * rd) };
        *(u16x4*)&attL[tok_l * 264 + cq] = res;
    }
    __syncthreads();

    // phase 2: MFMA projection
    int w = tid >> 6, lane = tid & 63, c16 = lane & 15, g = lane >> 4;
    int tg = w & 1, og = w >> 1;
    int n_tok = n0 + tg * 16 + c16;
    int o0 = og * 64;
    const unsigned short* Bsrc = &attL[(tg * 16 + c16) * 264 + g * 8];
    const unsigned short* Asrc = wo_bf + (size_t)(o0 + c16) * 256 + g * 8;
    f32x4 acc[4] = {};
    for (int kk = 0; kk < 8; ++kk) {
        bf16x8 bfr = ldbf8(Bsrc + kk * 32);
#pragma unroll
        for (int ot = 0; ot < 4; ++ot) {
            bf16x8 afr = ldbf8(Asrc + ot * 16 * 256 + kk * 32);
            acc[ot] = __builtin_amdgcn_mfma_f32_16x16x32_bf16(afr, bfr, acc[ot], 0, 0, 0);
        }
    }
#pragma unroll
    for (int ot = 0; ot < 4; ++ot) {
        int ob = o0 + ot * 16 + g * 4;
#pragma unroll
        for (int rr = 0; rr < 4; ++rr) {
            int o = ob + rr;
            size_t off = ((size_t)(b * NC + o)) * NT + n_tok;
            out[off] = acc[ot][rr] + bout[o] + x[off];
        }
    }
}

extern "C" void kernel_launch(void* const* d_in, const int* in_sizes, int n_in,
                              void* d_out, int out_size, void* d_ws, size_t ws_size,
                              hipStream_t stream) {
    const float* x    = (const float*)d_in[0];
    const float* nw   = (const float*)d_in[1];
    const float* nb   = (const float*)d_in[2];
    const float* wqkv = (const float*)d_in[3];
    const float* wout = (const float*)d_in[4];
    const float* bout = (const float*)d_in[5];
    float* out = (float*)d_out;
    char* wsb = (char*)d_ws;

    unsigned short* qkT = (unsigned short*)wsb;                        // 8 MB
    unsigned short* vbf = (unsigned short*)(wsb + 8u * 1024 * 1024);   // 4 MB
    unsigned short* pO  = (unsigned short*)(wsb + 12u * 1024 * 1024);  // 16 MB: [4ch][B][N][C] bf16
    float* pl   = (float*)(wsb + 28u * 1024 * 1024);                   // 1 MB
    float* part = (float*)(wsb + 29u * 1024 * 1024);
    unsigned short* wo_bf = (unsigned short*)(wsb + 30u * 1024 * 1024); // 128 KB
    // xnT (4 MB) and wq_bf (384 KB) alias the pO region: both dead before
    // k_attn writes pO (stream-ordered).
    unsigned short* xnT   = pO;                                        // @12 MB
    unsigned short* wq_bf = (unsigned short*)(wsb + 16u * 1024 * 1024);

    k_stats_wprep<<<640, 256, 0, stream>>>(x, part, wqkv, wout, wq_bf, wo_bf);
    k_xprep<<<dim3(NT / 64, NC / 64, NB), 256, 0, stream>>>(x, nw, nb, part, xnT);
    k_qkv_mfma<<<dim3(NT / 64, 6, NB), 256, 0, stream>>>(wq_bf, xnT, qkT, vbf);
    k_attn<<<dim3(NB * NCHUNK * NH * 32), 256, 0, stream>>>(qkT, vbf, pO, pl);
    k_out_fused<<<dim3(128, NB), 512, 0, stream>>>(pO, pl, wo_bf, bout, x, out);
}